// Round 5
// baseline (338.028 us; speedup 1.0000x reference)
//
#include <hip/hip_runtime.h>

#define HH 384
#define HWPX (HH*HH)

// ws float-offset layout
#define WOFF3 16
#define HS3   40      // D=3,  DP=4 : 2*3*4  + 3*4  + 4
#define WOFF6 256     // 16 + 6*40
#define HS6   328     // D=12, DP=12: 2*12*12+ 3*12 + 4
#define WOFF9 1568    // 256 + 4*328
#define HS9   1600    // D=27, DP=28: 2*27*28+ 3*28 + 4
#define CATOFF 8192

__device__ __forceinline__ float4 fma4s(float4 a, float4 w, float t) {
    a.x += w.x * t; a.y += w.y * t; a.z += w.z * t; a.w += w.w * t; return a;
}
__device__ __forceinline__ float dot4(float4 a, float4 b) {
    return a.x * b.x + a.y * b.y + a.z * b.z + a.w * b.w;
}
__device__ __forceinline__ float f4c(const float4& v, int j) {
    return j == 0 ? v.x : (j == 1 ? v.y : (j == 2 ? v.z : v.w));
}

// ---------------- precompute folded weights ----------------
__global__ __launch_bounds__(256) void pre_w(
    const float* __restrict__ w3q, const float* __restrict__ b3q,
    const float* __restrict__ w3k, const float* __restrict__ b3k,
    const float* __restrict__ w3v, const float* __restrict__ b3v, const float* __restrict__ hw3,
    const float* __restrict__ w6q, const float* __restrict__ b6q,
    const float* __restrict__ w6k, const float* __restrict__ b6k,
    const float* __restrict__ w6v, const float* __restrict__ b6v, const float* __restrict__ hw6,
    const float* __restrict__ w9q, const float* __restrict__ b9q,
    const float* __restrict__ w9k, const float* __restrict__ b9k,
    const float* __restrict__ w9v, const float* __restrict__ b9v, const float* __restrict__ hw9,
    float* __restrict__ ws)
{
    const int blk = blockIdx.x;
    const int tid = threadIdx.x;
    int stage = blk < 6 ? 0 : (blk < 10 ? 1 : 2);
    int h = blk - (stage == 0 ? 0 : (stage == 1 ? 6 : 10));
    const float* WQ[3] = {w3q, w6q, w9q};
    const float* BQ[3] = {b3q, b6q, b9q};
    const float* WK[3] = {w3k, w6k, w9k};
    const float* BK[3] = {b3k, b6k, b9k};
    const float* WV_[3] = {w3v, w6v, w9v};
    const float* BV[3] = {b3v, b6v, b9v};
    const float* HWp[3] = {hw3, hw6, hw9};
    const int Ds[3] = {3, 12, 27};
    const int DPs[3] = {4, 12, 28};
    const int WOFFs[3] = {WOFF3, WOFF6, WOFF9};
    const int HSs[3] = {HS3, HS6, HS9};

    const int D = Ds[stage], DP = DPs[stage];
    const float* wq = WQ[stage] + h * D * D;
    const float* bq = BQ[stage] + h * D;
    const float* wk = WK[stage] + h * D * D;
    const float* bk = BK[stage] + h * D;
    const float* wv = WV_[stage] + h * D * D;
    const float* bv = BV[stage] + h * D;
    const float hwv = HWp[stage][h];
    float* base = ws + WOFFs[stage] + h * HSs[stage];
    const float scale = rsqrtf((float)D);

    for (int i = tid; i < D * DP; i += 256) {
        int a = i / DP, b = i % DP;
        float m = 0.f;
        if (b < D) for (int e = 0; e < D; ++e) m += wk[e * D + b] * wq[e * D + a];
        base[i] = scale * m;                       // M[a][d]
        float wvv = 0.f;
        if (b < D) wvv = hwv * wv[a * D + b];
        base[D * DP + i] = wvv;                    // WV[e][d]
    }
    for (int i = tid; i < DP; i += 256) {
        float cv = 0.f, uv = 0.f;
        if (i < D) for (int e = 0; e < D; ++e) {
            cv += bq[e] * wk[e * D + i];
            uv += wq[e * D + i] * bk[e];
        }
        base[2 * D * DP + i] = scale * cv;         // c
        base[2 * D * DP + DP + i] = scale * uv;    // u
        base[2 * D * DP + 2 * DP + i] = (i < D) ? hwv * bv[i] : 0.f;   // bvh
    }
    if (tid == 0) {
        float s = 0.f;
        for (int e = 0; e < D; ++e) s += bq[e] * bk[e];
        base[2 * D * DP + 3 * DP] = scale * s;     // s0
    }
}

// ---------------- attention stage ----------------
// NT == NWX*NWY threads, one window each, all HEADS per thread.
template <int P, int HEADS, int NWX, int NWY, int NT, bool CELLREG, bool DO_XG>
__global__ __launch_bounds__(NT) void attn_k(
    const float* __restrict__ in, long in_bstride,
    float* __restrict__ out, long out_bstride,
    const float* __restrict__ wsw, float* __restrict__ xgws)
{
    constexpr int C = 3, D = C * P * P, DP = (D + 3) & ~3, NREG = DP / 4;
    constexpr int HS = 2 * D * DP + 3 * DP + 4;
    constexpr int CW = NWX + 2, CH = NWY + 2;
    constexpr int TC = CW * P, TR = CH * P;
    constexpr int NCHX = (TC + 3) / 4;
    constexpr int TOTC = C * TR * NCHX;
    constexpr int CPT = (TOTC + NT - 1) / NT;

    __shared__ __align__(16) float scell[CH * CW * DP];
    __shared__ __align__(16) float sw[HEADS * HS];

    const int tid = threadIdx.x;
    const int b = blockIdx.z;
    const int BWX = blockIdx.x * NWX, BWY = blockIdx.y * NWY;
    const int base_x = BWX * P - P, base_y = BWY * P - P;
    const float* inb = in + (size_t)b * in_bstride;

    {   // weights -> LDS (f4)
        const float4* src4 = (const float4*)wsw;
        float4* sw4 = (float4*)sw;
#pragma unroll
        for (int it = 0; it < (HEADS * HS / 4 + NT - 1) / NT; ++it) {
            int i = tid + it * NT;
            if (i < HEADS * HS / 4) sw4[i] = src4[i];
        }
    }

    float tmax = 0.f;
#pragma unroll
    for (int it = 0; it < CPT; ++it) {
        int idx = tid + it * NT;
        if (idx < TOTC) {
            int c = idx / (TR * NCHX);
            int rem = idx - c * (TR * NCHX);
            int row = rem / NCHX;
            int k = rem - row * NCHX;
            int gy = base_y + row; gy = gy < 0 ? -gy : (gy >= HH ? 2 * HH - 2 - gy : gy);
            int gx0 = base_x + 4 * k;
            const float* src = inb + c * HWPX + gy * HH;
            float v[4];
            if (gx0 >= 0 && gx0 + 4 <= HH) {
                float4 f = *(const float4*)(src + gx0);
                v[0] = f.x; v[1] = f.y; v[2] = f.z; v[3] = f.w;
            } else {
#pragma unroll
                for (int j = 0; j < 4; ++j) {
                    int gx = gx0 + j; gx = gx < 0 ? -gx : (gx >= HH ? 2 * HH - 2 - gx : gx);
                    v[j] = src[gx];
                }
            }
            const int nel = (4 * k + 4 <= TC) ? 4 : (TC - 4 * k);
            const int cy = row / P, r = row - cy * P;
#pragma unroll
            for (int j = 0; j < 4; ++j) {
                if (j < nel) {
                    int xx = 4 * k + j;
                    int cx = xx / P, s = xx - cx * P;
                    scell[(cy * CW + cx) * DP + (c * P + r) * P + s] = v[j];
                    if (DO_XG) tmax = fmaxf(tmax, v[j]);
                }
            }
        }
    }
    if constexpr (DP > D) {
        for (int i = tid; i < CH * CW; i += NT) scell[i * DP + D] = 0.f;
    }
    __syncthreads();

    if (DO_XG) {
        float m = tmax;
        for (int off = 32; off; off >>= 1) m = fmaxf(m, __shfl_down(m, off));
        if ((tid & 63) == 0) atomicMax((int*)xgws + b, __float_as_int(m));
    }

    const int wx = tid % NWX, wy = tid / NWX;
    const float4* cbase = (const float4*)scell;

    float4 Tc[CELLREG ? 9 : 1][NREG];
    float4 t4v[NREG];
    if constexpr (CELLREG) {
#pragma unroll
        for (int di = 0; di < 3; ++di)
#pragma unroll
            for (int dj = 0; dj < 3; ++dj) {
                const float4* p = cbase + ((size_t)(wy + di) * CW + (wx + dj)) * NREG;
#pragma unroll
                for (int kk = 0; kk < NREG; ++kk) Tc[di * 3 + dj][kk] = p[kk];
            }
    } else {
        const float4* p = cbase + ((size_t)(wy + 1) * CW + (wx + 1)) * NREG;
#pragma unroll
        for (int kk = 0; kk < NREG; ++kk) t4v[kk] = p[kk];
    }

    float mixed[D];
#pragma unroll
    for (int e = 0; e < D; ++e) mixed[e] = 0.f;

#pragma unroll 1
    for (int h = 0; h < HEADS; ++h) {
        const float* hb = &sw[h * HS];
        const float* ccb = hb + 2 * D * DP;
        float4 qk[NREG];
        {
            const float4* cp = (const float4*)ccb;
#pragma unroll
            for (int kk = 0; kk < NREG; ++kk) qk[kk] = cp[kk];
        }
        float su = ccb[3 * DP];
#pragma unroll
        for (int a = 0; a < D; ++a) {
            float t;
            if constexpr (CELLREG) t = f4c(Tc[4][a / 4], a & 3);
            else                   t = f4c(t4v[a / 4], a & 3);
            su += ccb[DP + a] * t;
            const float4* Mr = (const float4*)(hb + a * DP);
#pragma unroll
            for (int kk = 0; kk < NREG; ++kk) qk[kk] = fma4s(qk[kk], Mr[kk], t);
        }
        float denom = 0.f;
        float4 wt[NREG];
#pragma unroll
        for (int kk = 0; kk < NREG; ++kk) wt[kk] = make_float4(0.f, 0.f, 0.f, 0.f);
#pragma unroll
        for (int p9 = 0; p9 < 9; ++p9) {
            float4 cv[NREG];
            if constexpr (CELLREG) {
#pragma unroll
                for (int kk = 0; kk < NREG; ++kk) cv[kk] = Tc[p9][kk];
            } else {
                const int di = p9 / 3, dj = p9 % 3;
                const float4* p = cbase + ((size_t)(wy + di) * CW + (wx + dj)) * NREG;
#pragma unroll
                for (int kk = 0; kk < NREG; ++kk) cv[kk] = p[kk];
            }
            float s = su;
#pragma unroll
            for (int kk = 0; kk < NREG; ++kk) s += dot4(qk[kk], cv[kk]);
            const float e = __expf(s);
            denom += e;
#pragma unroll
            for (int kk = 0; kk < NREG; ++kk) wt[kk] = fma4s(wt[kk], cv[kk], e);
        }
        const float winv = 1.f / denom;
#pragma unroll
        for (int kk = 0; kk < NREG; ++kk) {
            wt[kk].x *= winv; wt[kk].y *= winv; wt[kk].z *= winv; wt[kk].w *= winv;
        }
        const float* WVb = hb + D * DP;
#pragma unroll
        for (int e = 0; e < D; ++e) {
            const float4* Wr = (const float4*)(WVb + e * DP);
            float o = ccb[2 * DP + e];
#pragma unroll
            for (int kk = 0; kk < NREG; ++kk) o += dot4(Wr[kk], wt[kk]);
            mixed[e] += o;
        }
    }

    float* outb = out + (size_t)b * out_bstride;
#pragma unroll
    for (int c = 0; c < C; ++c)
#pragma unroll
        for (int r = 0; r < P; ++r)
#pragma unroll
            for (int s = 0; s < P; ++s)
                outb[c * HWPX + ((BWY + wy) * P + r) * HH + (BWX + wx) * P + s] =
                    mixed[(c * P + r) * P + s];
}

// ---------------- conv0 (5x5, zero-pad 2) + final elementwise ----------------
__global__ __launch_bounds__(128) void conv_final(
    const float* __restrict__ cat,
    const float* __restrict__ w, const float* __restrict__ bias,
    const float* __restrict__ x, const float* __restrict__ xg,
    float* __restrict__ out)
{
    __shared__ float tile[9][20][40];
    const int tid = threadIdx.x;
    const int b = blockIdx.z;
    const int bx = blockIdx.x * 32, by = blockIdx.y * 16;
    const float* catb = cat + (size_t)b * 9 * HWPX;

#pragma unroll
    for (int it = 0; it < 15; ++it) {
        int i = tid + it * 128;
        if (i < 1800) {
            int ci = i / 200;
            int rem = i - ci * 200;
            int row = rem / 10, c4 = rem - row * 10;
            int y = by + row - 2, xx = bx - 4 + 4 * c4;
            float4 v = {0.f, 0.f, 0.f, 0.f};
            if (y >= 0 && y < HH && xx >= 0 && xx <= HH - 4)
                v = *(const float4*)&catb[ci * HWPX + y * HH + xx];
            *(float4*)&tile[ci][row][4 * c4] = v;
        }
    }
    __syncthreads();

    const int tx = tid & 7, ty = tid >> 3;
    float acc0[4], acc1[4], acc2[4];
    const float b0 = bias[0], b1 = bias[1], b2 = bias[2];
#pragma unroll
    for (int j = 0; j < 4; ++j) { acc0[j] = b0; acc1[j] = b1; acc2[j] = b2; }

#pragma unroll
    for (int ky = 0; ky < 5; ++ky) {
#pragma unroll 1
        for (int ci = 0; ci < 9; ++ci) {
            const float4 ra = *(const float4*)&tile[ci][ty + ky][4 * tx];
            const float4 rb = *(const float4*)&tile[ci][ty + ky][4 * tx + 4];
            const float4 rc = *(const float4*)&tile[ci][ty + ky][4 * tx + 8];
            const float r[12] = {ra.x, ra.y, ra.z, ra.w, rb.x, rb.y, rb.z, rb.w,
                                 rc.x, rc.y, rc.z, rc.w};
            const float* __restrict__ w0 = w + (0 * 9 + ci) * 25 + ky * 5;
            const float* __restrict__ w1 = w + (1 * 9 + ci) * 25 + ky * 5;
            const float* __restrict__ w2 = w + (2 * 9 + ci) * 25 + ky * 5;
#pragma unroll
            for (int j = 0; j < 4; ++j)
#pragma unroll
                for (int kx = 0; kx < 5; ++kx) {
                    const float t = r[j + kx + 2];
                    acc0[j] += t * w0[kx];
                    acc1[j] += t * w1[kx];
                    acc2[j] += t * w2[kx];
                }
        }
    }

    const int yb = by + ty, xb = bx + 4 * tx;
    const float xgv = xg[b];
    float* accs[3] = {acc0, acc1, acc2};
#pragma unroll
    for (int co = 0; co < 3; ++co) {
        const float4 xv = *(const float4*)&x[((size_t)(b * 3 + co)) * HWPX + yb * HH + xb];
        const float* a = accs[co];
        float4 ov;
        float x0;
        x0 = fmaxf(a[0], 0.f); ov.x = fmaxf(xv.x * x0 + xgv - x0, 0.f);
        x0 = fmaxf(a[1], 0.f); ov.y = fmaxf(xv.y * x0 + xgv - x0, 0.f);
        x0 = fmaxf(a[2], 0.f); ov.z = fmaxf(xv.z * x0 + xgv - x0, 0.f);
        x0 = fmaxf(a[3], 0.f); ov.w = fmaxf(xv.w * x0 + xgv - x0, 0.f);
        *(float4*)&out[((size_t)(b * 3 + co)) * HWPX + yb * HH + xb] = ov;
    }
}

// ---------------- launch ----------------
extern "C" void kernel_launch(void* const* d_in, const int* in_sizes, int n_in,
                              void* d_out, int out_size, void* d_ws, size_t ws_size,
                              hipStream_t stream) {
    const float* x   = (const float*)d_in[0];
    const float* w3q = (const float*)d_in[1];
    const float* b3q = (const float*)d_in[2];
    const float* w3k = (const float*)d_in[3];
    const float* b3k = (const float*)d_in[4];
    const float* w3v = (const float*)d_in[5];
    const float* b3v = (const float*)d_in[6];
    const float* hw3 = (const float*)d_in[7];
    const float* w6q = (const float*)d_in[8];
    const float* b6q = (const float*)d_in[9];
    const float* w6k = (const float*)d_in[10];
    const float* b6k = (const float*)d_in[11];
    const float* w6v = (const float*)d_in[12];
    const float* b6v = (const float*)d_in[13];
    const float* hw6 = (const float*)d_in[14];
    const float* w9q = (const float*)d_in[15];
    const float* b9q = (const float*)d_in[16];
    const float* w9k = (const float*)d_in[17];
    const float* b9k = (const float*)d_in[18];
    const float* w9v = (const float*)d_in[19];
    const float* b9v = (const float*)d_in[20];
    const float* hw9 = (const float*)d_in[21];
    const float* c0w = (const float*)d_in[22];
    const float* c0b = (const float*)d_in[23];

    float* out = (float*)d_out;
    float* ws  = (float*)d_ws;
    float* cat = ws + CATOFF;

    pre_w<<<12, 256, 0, stream>>>(
        w3q, b3q, w3k, b3k, w3v, b3v, hw3,
        w6q, b6q, w6k, b6k, w6v, b6v, hw6,
        w9q, b9q, w9k, b9k, w9v, b9v, hw9, ws);

    // stage3: p=1, 6 heads, 16x16 windows/block, fused xg max -> cat ch6..8
    attn_k<1, 6, 16, 16, 256, true, true><<<dim3(24, 24, 2), 256, 0, stream>>>(
        x, 3 * HWPX, cat + 6 * HWPX, 9 * HWPX, ws + WOFF3, ws);
    // stage6: p=2, 4 heads, 8x8 windows/block -> cat ch3..5
    attn_k<2, 4, 8, 8, 64, true, false><<<dim3(24, 24, 2), 64, 0, stream>>>(
        cat + 6 * HWPX, 9 * HWPX, cat + 3 * HWPX, 9 * HWPX, ws + WOFF6, ws);
    // stage9: p=3, 2 heads, 8x8 windows/block -> cat ch0..2
    attn_k<3, 2, 8, 8, 64, false, false><<<dim3(16, 16, 2), 64, 0, stream>>>(
        cat + 3 * HWPX, 9 * HWPX, cat, 9 * HWPX, ws + WOFF9, ws);

    conv_final<<<dim3(12, 24, 2), 128, 0, stream>>>(cat, c0w, c0b, x, ws, out);
}

// Round 6
// 309.395 us; speedup vs baseline: 1.0925x; 1.0925x over previous
//
#include <hip/hip_runtime.h>

#define HH 384
#define HWPX (HH*HH)

// ws float-offset layout (global scratch): ws[0..1]=xg, folded weights at [16,4768)
#define WOFF3 16
#define HS3   40      // D=3,  DP=4
#define WOFF6 256
#define HS6   328     // D=12, DP=12
#define WOFF9 1568
#define HS9   1600    // D=27, DP=28

__device__ __forceinline__ int rx(int g) {
    g = g < 0 ? -g : g;
    return g >= HH ? 2 * HH - 2 - g : g;
}
__device__ __forceinline__ float4 fma4s(float4 a, float4 w, float t) {
    a.x += w.x * t; a.y += w.y * t; a.z += w.z * t; a.w += w.w * t; return a;
}
__device__ __forceinline__ float dot4(float4 a, float4 b) {
    return a.x * b.x + a.y * b.y + a.z * b.z + a.w * b.w;
}
__device__ __forceinline__ float f4c(const float4& v, int j) {
    return j == 0 ? v.x : (j == 1 ? v.y : (j == 2 ? v.z : v.w));
}

// ---------------- k1: fold weights (blocks 0..11) + xg max (blocks 12..299) ----------------
__global__ __launch_bounds__(256) void pre_xg(
    const float* __restrict__ w3q, const float* __restrict__ b3q,
    const float* __restrict__ w3k, const float* __restrict__ b3k,
    const float* __restrict__ w3v, const float* __restrict__ b3v, const float* __restrict__ hw3,
    const float* __restrict__ w6q, const float* __restrict__ b6q,
    const float* __restrict__ w6k, const float* __restrict__ b6k,
    const float* __restrict__ w6v, const float* __restrict__ b6v, const float* __restrict__ hw6,
    const float* __restrict__ w9q, const float* __restrict__ b9q,
    const float* __restrict__ w9k, const float* __restrict__ b9k,
    const float* __restrict__ w9v, const float* __restrict__ b9v, const float* __restrict__ hw9,
    const float* __restrict__ x, float* __restrict__ ws)
{
    __shared__ float sm[4];
    const int blk = blockIdx.x;
    const int tid = threadIdx.x;

    if (blk < 12) {
        int stage = blk < 6 ? 0 : (blk < 10 ? 1 : 2);
        int h = blk - (stage == 0 ? 0 : (stage == 1 ? 6 : 10));
        const float* WQ[3] = {w3q, w6q, w9q};
        const float* BQ[3] = {b3q, b6q, b9q};
        const float* WK[3] = {w3k, w6k, w9k};
        const float* BK[3] = {b3k, b6k, b9k};
        const float* WV_[3] = {w3v, w6v, w9v};
        const float* BV[3] = {b3v, b6v, b9v};
        const float* HWp[3] = {hw3, hw6, hw9};
        const int Ds[3] = {3, 12, 27};
        const int DPs[3] = {4, 12, 28};
        const int WOFFs[3] = {WOFF3, WOFF6, WOFF9};
        const int HSs[3] = {HS3, HS6, HS9};

        const int D = Ds[stage], DP = DPs[stage];
        const float* wq = WQ[stage] + h * D * D;
        const float* bq = BQ[stage] + h * D;
        const float* wk = WK[stage] + h * D * D;
        const float* bk = BK[stage] + h * D;
        const float* wv = WV_[stage] + h * D * D;
        const float* bv = BV[stage] + h * D;
        const float hwv = HWp[stage][h];
        float* base = ws + WOFFs[stage] + h * HSs[stage];
        const float scale = rsqrtf((float)D);

        for (int i = tid; i < D * DP; i += 256) {
            int a = i / DP, b = i % DP;
            float m = 0.f;
            if (b < D) for (int e = 0; e < D; ++e) m += wk[e * D + b] * wq[e * D + a];
            base[i] = scale * m;                       // M[a][d]  (pad cols = 0)
            float wvv = 0.f;
            if (b < D) wvv = hwv * wv[a * D + b];
            base[D * DP + i] = wvv;                    // WV[e][d] (pad cols = 0)
        }
        for (int i = tid; i < DP; i += 256) {
            float cv = 0.f, uv = 0.f;
            if (i < D) for (int e = 0; e < D; ++e) {
                cv += bq[e] * wk[e * D + i];
                uv += wq[e * D + i] * bk[e];
            }
            base[2 * D * DP + i] = scale * cv;         // c (pad = 0)
            base[2 * D * DP + DP + i] = scale * uv;    // u (pad = 0)
            base[2 * D * DP + 2 * DP + i] = (i < D) ? hwv * bv[i] : 0.f;   // bvh
        }
        if (tid == 0) {
            float s = 0.f;
            for (int e = 0; e < D; ++e) s += bq[e] * bk[e];
            base[2 * D * DP + 3 * DP] = scale * s;     // s0
        }
    } else {
        int i2 = blk - 12;
        int b = i2 / 144, chunk = i2 % 144;
        const float4* xb = (const float4*)(x + (size_t)b * 3 * HWPX + chunk * 3072);
        float m = 0.f;
        for (int j = tid; j < 768; j += 256) {
            float4 v = xb[j];
            m = fmaxf(m, fmaxf(fmaxf(v.x, v.y), fmaxf(v.z, v.w)));
        }
        for (int off = 32; off; off >>= 1)
            m = fmaxf(m, __shfl_down(m, off));
        if ((tid & 63) == 0) sm[tid >> 6] = m;
        __syncthreads();
        if (tid == 0) {
            float mm = fmaxf(fmaxf(sm[0], sm[1]), fmaxf(sm[2], sm[3]));
            atomicMax((int*)&ws[b], __float_as_int(mm));  // poison is negative int; mm>=0 wins
        }
    }
}

// ---------------- k2: fully fused pipeline, one block = one 48x32 output tile ----------------
// LDS layout (floats):
//   [0, 12096)      X staged input [3][56][72]  (dead after stage3)
//                     -> X9 pixel [3][36][52] @0 (5616), X6pix [3][36][52] @5616
//   [12096, 17528)  weights: s3 @+0 (240), s6 @+240 (1312), s9 @+1552 (3200),
//                   convw @+4752 (675), convb @+5427 (3)
//   [17528, 25928)  X6 cells [15][20][28]  (300 cells, pad elem 27 zeroed)
//   [25928, 36536)  X3 cells [26][34][12]  (884 cells)
__global__ __launch_bounds__(512, 2) void mega(
    const float* __restrict__ x, const float* __restrict__ wsg,
    float* __restrict__ out)
{
    __shared__ float L[36536];
    const int tid = threadIdx.x;
    const int X0 = blockIdx.x * 48, Y0 = blockIdx.y * 32, b = blockIdx.z;
    const int OXx = X0 - 12, OXy = Y0 - 12;
    const int C3X = X0 / 2 - 5, C3Y = Y0 / 2 - 5;
    const int m9y = (Y0 + 1) / 3 - 1;           // floor((Y0-2)/3)
    const int m9x = X0 / 3 - 1;
    const int C6X = X0 / 3 - 2, C6Y = m9y - 1;
    const float* xb = x + (size_t)b * 3 * HWPX;

    // ---- P0: stage X (reflect), weights, conv w/b, zero X6 pad lanes ----
    for (int i = tid; i < 3 * 56 * 18; i += 512) {
        int c = i / (56 * 18);
        int rem = i - c * 56 * 18;
        int row = rem / 18, ck = rem % 18;
        int gy = rx(OXy + row);
        int gx0 = OXx + 4 * ck;
        const float* src = xb + c * HWPX + gy * HH;
        float4 v;
        if (gx0 >= 0 && gx0 + 4 <= HH) v = *(const float4*)(src + gx0);
        else { v.x = src[rx(gx0)]; v.y = src[rx(gx0 + 1)]; v.z = src[rx(gx0 + 2)]; v.w = src[rx(gx0 + 3)]; }
        *(float4*)&L[c * 4032 + row * 72 + 4 * ck] = v;
    }
    for (int i = tid; i < 1188; i += 512)
        *(float4*)&L[12096 + 4 * i] = *(const float4*)&wsg[WOFF3 + 4 * i];
    for (int i = tid; i < 678; i += 512)
        L[12096 + 4752 + i] = wsg[0] * 0.f + ((i < 675) ? 0.f : 0.f);  // placeholder overwritten below
    __syncthreads();  // (conv weights loaded in launch via params; see below)
    // NOTE: conv weights come from their own global arrays; stage them now:
    // (kept separate loop to keep P0 simple; wsg holds only attention weights)

    // ---- actually stage conv weights + zero pads (small) ----
    // convw/convb passed via wsg tail? No: they are separate inputs; see kernel_launch:
    // we copy them into ws[4768..5446) there-less; instead mega reads them via extra params.
    __syncthreads();
    // (see mega2 below -- this kernel body continues in mega_impl)
    (void)out;
}

// The real mega kernel (with conv weight params). The stub above is unused.
__global__ __launch_bounds__(512, 2) void mega2(
    const float* __restrict__ x, const float* __restrict__ wsg,
    const float* __restrict__ convw, const float* __restrict__ convb,
    float* __restrict__ out)
{
    __shared__ float L[36536];
    const int tid = threadIdx.x;
    const int X0 = blockIdx.x * 48, Y0 = blockIdx.y * 32, b = blockIdx.z;
    const int OXx = X0 - 12, OXy = Y0 - 12;
    const int C3X = X0 / 2 - 5, C3Y = Y0 / 2 - 5;
    const int m9y = (Y0 + 1) / 3 - 1;           // floor((Y0-2)/3)
    const int m9x = X0 / 3 - 1;
    const int C6X = X0 / 3 - 2, C6Y = m9y - 1;
    const float* xb = x + (size_t)b * 3 * HWPX;
    const bool border = (X0 == 0) || (X0 == 336) || (Y0 == 0) || (Y0 == 352);

    // ---- P0 ----
    for (int i = tid; i < 3 * 56 * 18; i += 512) {
        int c = i / (56 * 18);
        int rem = i - c * 56 * 18;
        int row = rem / 18, ck = rem % 18;
        int gy = rx(OXy + row);
        int gx0 = OXx + 4 * ck;
        const float* src = xb + c * HWPX + gy * HH;
        float4 v;
        if (gx0 >= 0 && gx0 + 4 <= HH) v = *(const float4*)(src + gx0);
        else { v.x = src[rx(gx0)]; v.y = src[rx(gx0 + 1)]; v.z = src[rx(gx0 + 2)]; v.w = src[rx(gx0 + 3)]; }
        *(float4*)&L[c * 4032 + row * 72 + 4 * ck] = v;
    }
    for (int i = tid; i < 1188; i += 512)
        *(float4*)&L[12096 + 4 * i] = *(const float4*)&wsg[WOFF3 + 4 * i];
    for (int i = tid; i < 678; i += 512)
        L[12096 + 4752 + i] = (i < 675) ? convw[i] : convb[i - 675];
    for (int i = tid; i < 300; i += 512) L[17528 + i * 28 + 27] = 0.f;
    __syncthreads();

    // ---- P1: stage3 (p=1, 6 heads) -> X3 cells ----
    for (int l = tid; l < 68 * 52; l += 512) {
        int lx = l % 68, ly = l / 68;
        int gx = X0 - 10 + lx, gy = Y0 - 10 + ly;
        if (gx < 0 || gx >= HH || gy < 0 || gy >= HH) continue;
        float4 T[9];
#pragma unroll
        for (int di = 0; di < 3; ++di)
#pragma unroll
            for (int dj = 0; dj < 3; ++dj) {
                int ax = lx + 1 + dj, ay = ly + 1 + di;
                T[di * 3 + dj] = make_float4(L[ay * 72 + ax], L[4032 + ay * 72 + ax],
                                             L[8064 + ay * 72 + ax], 0.f);
            }
        float m0 = 0.f, m1 = 0.f, m2 = 0.f;
#pragma unroll 1
        for (int h = 0; h < 6; ++h) {
            const float* hb = &L[12096 + h * 40];
            float4 qk = *(const float4*)(hb + 24);
            float su = hb[36] + dot4(*(const float4*)(hb + 28), T[4]);
            qk = fma4s(qk, *(const float4*)(hb + 0), T[4].x);
            qk = fma4s(qk, *(const float4*)(hb + 4), T[4].y);
            qk = fma4s(qk, *(const float4*)(hb + 8), T[4].z);
            float den = 0.f; float4 wt = {0.f, 0.f, 0.f, 0.f};
#pragma unroll
            for (int p = 0; p < 9; ++p) {
                float e = __expf(su + dot4(qk, T[p]));
                den += e; wt = fma4s(wt, T[p], e);
            }
            float wi = 1.f / den;
            wt.x *= wi; wt.y *= wi; wt.z *= wi; wt.w *= wi;
            m0 += hb[32] + dot4(*(const float4*)(hb + 12), wt);
            m1 += hb[33] + dot4(*(const float4*)(hb + 16), wt);
            m2 += hb[34] + dot4(*(const float4*)(hb + 20), wt);
        }
        float* cell = &L[25928 + ((ly >> 1) * 34 + (lx >> 1)) * 12 + (ly & 1) * 2 + (lx & 1)];
        cell[0] = m0; cell[4] = m1; cell[8] = m2;
    }
    __syncthreads();

    // ---- P1b: X3 reflect-halo (border blocks only) ----
    if (border) {
        for (int l = tid; l < 884; l += 512) {
            int lcx = l % 34, lcy = l / 34;
            int gcx = C3X + lcx, gcy = C3Y + lcy;
            if (gcx >= 0 && gcx < 192 && gcy >= 0 && gcy < 192) continue;
            float* dst = &L[25928 + l * 12];
#pragma unroll
            for (int rr = 0; rr < 2; ++rr)
#pragma unroll
                for (int ss = 0; ss < 2; ++ss) {
                    int rpy = rx(2 * gcy + rr), rpx = rx(2 * gcx + ss);
                    const float* src = &L[25928 + (((rpy >> 1) - C3Y) * 34 + ((rpx >> 1) - C3X)) * 12
                                          + (rpy & 1) * 2 + (rpx & 1)];
                    dst[rr * 2 + ss] = src[0];
                    dst[4 + rr * 2 + ss] = src[4];
                    dst[8 + rr * 2 + ss] = src[8];
                }
        }
    }
    __syncthreads();

    // ---- P2: stage6 (p=2, 4 heads) -> X6 cells ----
    for (int l = tid; l < 768; l += 512) {
        int lwx = l % 32, lwy = l / 32;
        int gwx = X0 / 2 - 4 + lwx, gwy = Y0 / 2 - 4 + lwy;
        if (gwx < 0 || gwx >= 192 || gwy < 0 || gwy >= 192) continue;
        float4 T[9][3];
#pragma unroll
        for (int di = 0; di < 3; ++di)
#pragma unroll
            for (int dj = 0; dj < 3; ++dj) {
                const float4* cp = (const float4*)&L[25928 + ((lwy + di) * 34 + (lwx + dj)) * 12];
                T[di * 3 + dj][0] = cp[0]; T[di * 3 + dj][1] = cp[1]; T[di * 3 + dj][2] = cp[2];
            }
        float mixed[12];
#pragma unroll
        for (int e = 0; e < 12; ++e) mixed[e] = 0.f;
#pragma unroll 1
        for (int h = 0; h < 4; ++h) {
            const float* hb = &L[12096 + 240 + h * 328];
            float4 qk0 = *(const float4*)(hb + 288);
            float4 qk1 = *(const float4*)(hb + 292);
            float4 qk2 = *(const float4*)(hb + 296);
            float su = hb[324];
#pragma unroll
            for (int a = 0; a < 12; ++a) {
                float t = f4c(T[4][a >> 2], a & 3);
                su += hb[300 + a] * t;
                const float4* Mr = (const float4*)(hb + 12 * a);
                qk0 = fma4s(qk0, Mr[0], t);
                qk1 = fma4s(qk1, Mr[1], t);
                qk2 = fma4s(qk2, Mr[2], t);
            }
            float den = 0.f;
            float4 wt0 = {0,0,0,0}, wt1 = {0,0,0,0}, wt2 = {0,0,0,0};
#pragma unroll
            for (int p = 0; p < 9; ++p) {
                float s = su + dot4(qk0, T[p][0]) + dot4(qk1, T[p][1]) + dot4(qk2, T[p][2]);
                float e = __expf(s);
                den += e;
                wt0 = fma4s(wt0, T[p][0], e);
                wt1 = fma4s(wt1, T[p][1], e);
                wt2 = fma4s(wt2, T[p][2], e);
            }
            float wi = 1.f / den;
            wt0.x *= wi; wt0.y *= wi; wt0.z *= wi; wt0.w *= wi;
            wt1.x *= wi; wt1.y *= wi; wt1.z *= wi; wt1.w *= wi;
            wt2.x *= wi; wt2.y *= wi; wt2.z *= wi; wt2.w *= wi;
#pragma unroll
            for (int e = 0; e < 12; ++e) {
                const float4* Wr = (const float4*)(hb + 144 + 12 * e);
                mixed[e] += hb[312 + e] + dot4(Wr[0], wt0) + dot4(Wr[1], wt1) + dot4(Wr[2], wt2);
            }
        }
#pragma unroll
        for (int c = 0; c < 3; ++c)
#pragma unroll
            for (int r2 = 0; r2 < 2; ++r2)
#pragma unroll
                for (int s2 = 0; s2 < 2; ++s2) {
                    int gpy = 2 * gwy + r2, gpx = 2 * gwx + s2;
                    int q3y = gpy / 3, q3x = gpx / 3;
                    int lcy = q3y - C6Y, lcx = q3x - C6X;
                    if (lcx < 0 || lcx >= 20 || lcy < 0 || lcy >= 15) continue;
                    L[17528 + (lcy * 20 + lcx) * 28 + c * 9 + (gpy - 3 * q3y) * 3 + (gpx - 3 * q3x)]
                        = mixed[(c * 2 + r2) * 2 + s2];
                }
    }
    __syncthreads();

    // ---- P2b: X6 reflect-halo (border blocks only) ----
    if (border) {
        for (int l = tid; l < 300; l += 512) {
            int lcx = l % 20, lcy = l / 20;
            int gcx = C6X + lcx, gcy = C6Y + lcy;
            if (gcx >= 0 && gcx < 128 && gcy >= 0 && gcy < 128) continue;
            float* dst = &L[17528 + l * 28];
            for (int e = 0; e < 27; ++e) {
                int c = e / 9, r9 = (e % 9) / 3, s9 = e % 3;
                int rpy = rx(3 * gcy + r9), rpx = rx(3 * gcx + s9);
                dst[e] = L[17528 + (((rpy / 3) - C6Y) * 20 + ((rpx / 3) - C6X)) * 28
                           + c * 9 + (rpy % 3) * 3 + (rpx % 3)];
            }
        }
    }
    __syncthreads();

    // ---- P3: stage9 (p=3, 2 heads) -> X9 pixels (into dead X region) ----
    if (tid < 234) {
        int lwx = tid % 18, lwy = tid / 18;
        int gwx = m9x + lwx, gwy = m9y + lwy;
        if (gwx >= 0 && gwx < 128 && gwy >= 0 && gwy < 128) {
            const float4* cc = (const float4*)&L[17528 + ((lwy + 1) * 20 + (lwx + 1)) * 28];
            float4 t9[7];
#pragma unroll
            for (int k = 0; k < 7; ++k) t9[k] = cc[k];
            float mixed[27];
#pragma unroll
            for (int e = 0; e < 27; ++e) mixed[e] = 0.f;
#pragma unroll 1
            for (int h = 0; h < 2; ++h) {
                const float* hb = &L[12096 + 1552 + h * 1600];
                float4 qk[7];
#pragma unroll
                for (int k = 0; k < 7; ++k) qk[k] = *(const float4*)(hb + 1512 + 4 * k);
                float su = hb[1596];
#pragma unroll
                for (int a = 0; a < 27; ++a) {
                    float t = f4c(t9[a >> 2], a & 3);
                    su += hb[1540 + a] * t;
                    const float4* Mr = (const float4*)(hb + 28 * a);
#pragma unroll
                    for (int k = 0; k < 7; ++k) qk[k] = fma4s(qk[k], Mr[k], t);
                }
                float den = 0.f;
                float4 wt[7];
#pragma unroll
                for (int k = 0; k < 7; ++k) wt[k] = make_float4(0.f, 0.f, 0.f, 0.f);
#pragma unroll 1
                for (int p = 0; p < 9; ++p) {
                    int di = p / 3, dj = p % 3;
                    const float4* cv = (const float4*)&L[17528 + ((lwy + di) * 20 + (lwx + dj)) * 28];
                    float s = su;
                    float4 c0 = cv[0], c1 = cv[1], c2 = cv[2], c3 = cv[3],
                           c4 = cv[4], c5 = cv[5], c6 = cv[6];
                    s += dot4(qk[0], c0) + dot4(qk[1], c1) + dot4(qk[2], c2) + dot4(qk[3], c3)
                       + dot4(qk[4], c4) + dot4(qk[5], c5) + dot4(qk[6], c6);
                    float e = __expf(s);
                    den += e;
                    wt[0] = fma4s(wt[0], c0, e); wt[1] = fma4s(wt[1], c1, e);
                    wt[2] = fma4s(wt[2], c2, e); wt[3] = fma4s(wt[3], c3, e);
                    wt[4] = fma4s(wt[4], c4, e); wt[5] = fma4s(wt[5], c5, e);
                    wt[6] = fma4s(wt[6], c6, e);
                }
                float wi = 1.f / den;
#pragma unroll
                for (int k = 0; k < 7; ++k) { wt[k].x *= wi; wt[k].y *= wi; wt[k].z *= wi; wt[k].w *= wi; }
#pragma unroll
                for (int e = 0; e < 27; ++e) {
                    const float4* Wr = (const float4*)(hb + 756 + 28 * e);
                    float o = hb[1568 + e];
#pragma unroll
                    for (int k = 0; k < 7; ++k) o += dot4(Wr[k], wt[k]);
                    mixed[e] += o;
                }
            }
#pragma unroll
            for (int c = 0; c < 3; ++c)
#pragma unroll
                for (int r9 = 0; r9 < 3; ++r9)
#pragma unroll
                    for (int s9 = 0; s9 < 3; ++s9) {
                        int ly = 3 * gwy + r9 - (Y0 - 2), lx = 3 * gwx + s9 - (X0 - 2);
                        if (lx >= 0 && lx < 52 && ly >= 0 && ly < 36)
                            L[c * 1872 + ly * 52 + lx] = mixed[c * 9 + r9 * 3 + s9];
                    }
        }
    }
    __syncthreads();

    // ---- P3b: zero invalid X9 px; build X6 pixel view @5616 ----
    for (int i = tid; i < 5616; i += 512) {
        int c = i / 1872, rem = i % 1872;
        int ly = rem / 52, lx = rem % 52;
        int gy = Y0 - 2 + ly, gx = X0 - 2 + lx;
        bool in = (gy >= 0 && gy < HH && gx >= 0 && gx < HH);
        if (!in) L[i] = 0.f;
        float v6 = 0.f;
        if (in) {
            int q3y = gy / 3, q3x = gx / 3;
            v6 = L[17528 + ((q3y - C6Y) * 20 + (q3x - C6X)) * 28 + c * 9
                   + (gy - 3 * q3y) * 3 + (gx - 3 * q3x)];
        }
        L[5616 + i] = v6;
    }
    __syncthreads();

    // ---- P4: conv 5x5 (zero-pad) + final elementwise; 3 px per thread ----
    {
        const float xg = wsg[b];
        int pxl[3], pyl[3];
        float acc[3][3];
        const float b0 = L[12096 + 5427 + 0], b1 = L[12096 + 5427 + 1], b2 = L[12096 + 5427 + 2];
#pragma unroll
        for (int j = 0; j < 3; ++j) {
            int l = tid + j * 512;
            pxl[j] = l % 48; pyl[j] = l / 48;
            acc[0][j] = b0; acc[1][j] = b1; acc[2][j] = b2;
        }
#pragma unroll 1
        for (int ky = 0; ky < 5; ++ky) {
#pragma unroll 1
            for (int kx = 0; kx < 5; ++kx) {
#pragma unroll 1
                for (int ci = 0; ci < 9; ++ci) {
                    const float w0 = L[12096 + 4752 + (0 * 9 + ci) * 25 + ky * 5 + kx];
                    const float w1 = L[12096 + 4752 + (1 * 9 + ci) * 25 + ky * 5 + kx];
                    const float w2 = L[12096 + 4752 + (2 * 9 + ci) * 25 + ky * 5 + kx];
#pragma unroll
                    for (int j = 0; j < 3; ++j) {
                        int gy = Y0 + pyl[j] + ky - 2, gx = X0 + pxl[j] + kx - 2;
                        float t = 0.f;
                        if (gy >= 0 && gy < HH && gx >= 0 && gx < HH) {
                            if (ci < 6) {
                                t = L[(ci < 3 ? 0 : 5616) + (ci % 3) * 1872
                                      + (pyl[j] + ky) * 52 + pxl[j] + kx];
                            } else {
                                t = L[25928 + (((gy >> 1) - C3Y) * 34 + ((gx >> 1) - C3X)) * 12
                                      + (ci - 6) * 4 + (gy & 1) * 2 + (gx & 1)];
                            }
                        }
                        acc[0][j] += t * w0; acc[1][j] += t * w1; acc[2][j] += t * w2;
                    }
                }
            }
        }
#pragma unroll
        for (int j = 0; j < 3; ++j) {
            int gy = Y0 + pyl[j], gx = X0 + pxl[j];
#pragma unroll
            for (int co = 0; co < 3; ++co) {
                float x0 = fmaxf(acc[co][j], 0.f);
                float xv = xb[co * HWPX + gy * HH + gx];
                out[((size_t)(b * 3 + co)) * HWPX + gy * HH + gx] = fmaxf(xv * x0 + xg - x0, 0.f);
            }
        }
    }
}

// ---------------- launch ----------------
extern "C" void kernel_launch(void* const* d_in, const int* in_sizes, int n_in,
                              void* d_out, int out_size, void* d_ws, size_t ws_size,
                              hipStream_t stream) {
    const float* x   = (const float*)d_in[0];
    const float* w3q = (const float*)d_in[1];
    const float* b3q = (const float*)d_in[2];
    const float* w3k = (const float*)d_in[3];
    const float* b3k = (const float*)d_in[4];
    const float* w3v = (const float*)d_in[5];
    const float* b3v = (const float*)d_in[6];
    const float* hw3 = (const float*)d_in[7];
    const float* w6q = (const float*)d_in[8];
    const float* b6q = (const float*)d_in[9];
    const float* w6k = (const float*)d_in[10];
    const float* b6k = (const float*)d_in[11];
    const float* w6v = (const float*)d_in[12];
    const float* b6v = (const float*)d_in[13];
    const float* hw6 = (const float*)d_in[14];
    const float* w9q = (const float*)d_in[15];
    const float* b9q = (const float*)d_in[16];
    const float* w9k = (const float*)d_in[17];
    const float* b9k = (const float*)d_in[18];
    const float* w9v = (const float*)d_in[19];
    const float* b9v = (const float*)d_in[20];
    const float* hw9 = (const float*)d_in[21];
    const float* c0w = (const float*)d_in[22];
    const float* c0b = (const float*)d_in[23];

    float* out = (float*)d_out;
    float* ws  = (float*)d_ws;

    pre_xg<<<300, 256, 0, stream>>>(
        w3q, b3q, w3k, b3k, w3v, b3v, hw3,
        w6q, b6q, w6k, b6k, w6v, b6v, hw6,
        w9q, b9q, w9k, b9k, w9v, b9v, hw9, x, ws);

    mega2<<<dim3(8, 12, 2), 512, 0, stream>>>(x, ws, c0w, c0b, out);
}

// Round 7
// 195.650 us; speedup vs baseline: 1.7277x; 1.5814x over previous
//
#include <hip/hip_runtime.h>

#define HH 384
#define HWPX (HH*HH)

// ws float-offset layout: ws[0..1] = xg, folded weights:
#define WOFF3 16
#define HS3   40      // D=3,  DP=4 : 2*3*4 + 3*4 + 4
#define WOFF6 256     // 16 + 6*40
#define HS6   328     // D=12, DP=12
#define WOFF9 1568    // 256 + 4*328
#define HS9   1828    // D=27, DP=32 : 2*27*32 + 3*32 + 4
#define CATOFF 8192   // cat [2][9][384][384] floats

__device__ __forceinline__ int rx(int g) {
    g = g < 0 ? -g : g;
    return g >= HH ? 2 * HH - 2 - g : g;
}
__device__ __forceinline__ float4 fma4s(float4 a, float4 w, float t) {
    a.x += w.x * t; a.y += w.y * t; a.z += w.z * t; a.w += w.w * t; return a;
}
__device__ __forceinline__ float dot4(float4 a, float4 b) {
    return a.x * b.x + a.y * b.y + a.z * b.z + a.w * b.w;
}
__device__ __forceinline__ float f4c(const float4& v, int j) {
    return j == 0 ? v.x : (j == 1 ? v.y : (j == 2 ? v.z : v.w));
}

// ---------------- k1: fold weights (blocks 0..11) + xg max (blocks 12..299) ----------------
__global__ __launch_bounds__(256) void pre_xg(
    const float* __restrict__ w3q, const float* __restrict__ b3q,
    const float* __restrict__ w3k, const float* __restrict__ b3k,
    const float* __restrict__ w3v, const float* __restrict__ b3v, const float* __restrict__ hw3,
    const float* __restrict__ w6q, const float* __restrict__ b6q,
    const float* __restrict__ w6k, const float* __restrict__ b6k,
    const float* __restrict__ w6v, const float* __restrict__ b6v, const float* __restrict__ hw6,
    const float* __restrict__ w9q, const float* __restrict__ b9q,
    const float* __restrict__ w9k, const float* __restrict__ b9k,
    const float* __restrict__ w9v, const float* __restrict__ b9v, const float* __restrict__ hw9,
    const float* __restrict__ x, float* __restrict__ ws)
{
    __shared__ float sm[4];
    const int blk = blockIdx.x;
    const int tid = threadIdx.x;

    if (blk < 12) {
        int stage = blk < 6 ? 0 : (blk < 10 ? 1 : 2);
        int h = blk - (stage == 0 ? 0 : (stage == 1 ? 6 : 10));
        const float* WQ[3] = {w3q, w6q, w9q};
        const float* BQ[3] = {b3q, b6q, b9q};
        const float* WK[3] = {w3k, w6k, w9k};
        const float* BK[3] = {b3k, b6k, b9k};
        const float* WV_[3] = {w3v, w6v, w9v};
        const float* BV[3] = {b3v, b6v, b9v};
        const float* HWp[3] = {hw3, hw6, hw9};
        const int Ds[3] = {3, 12, 27};
        const int DPs[3] = {4, 12, 32};      // stage9 padded to 32 for 4-lane teams
        const int WOFFs[3] = {WOFF3, WOFF6, WOFF9};
        const int HSs[3] = {HS3, HS6, HS9};

        const int D = Ds[stage], DP = DPs[stage];
        const float* wq = WQ[stage] + h * D * D;
        const float* bq = BQ[stage] + h * D;
        const float* wk = WK[stage] + h * D * D;
        const float* bk = BK[stage] + h * D;
        const float* wv = WV_[stage] + h * D * D;
        const float* bv = BV[stage] + h * D;
        const float hwv = HWp[stage][h];
        float* base = ws + WOFFs[stage] + h * HSs[stage];
        const float scale = rsqrtf((float)D);

        for (int i = tid; i < D * DP; i += 256) {
            int a = i / DP, b = i % DP;
            float m = 0.f;
            if (b < D) for (int e = 0; e < D; ++e) m += wk[e * D + b] * wq[e * D + a];
            base[i] = scale * m;                       // M[a][d], pad cols = 0
            float wvv = 0.f;
            if (b < D) wvv = hwv * wv[a * D + b];
            base[D * DP + i] = wvv;                    // WV[e][d], pad cols = 0
        }
        for (int i = tid; i < DP; i += 256) {
            float cv = 0.f, uv = 0.f;
            if (i < D) for (int e = 0; e < D; ++e) {
                cv += bq[e] * wk[e * D + i];
                uv += wq[e * D + i] * bk[e];
            }
            base[2 * D * DP + i] = scale * cv;         // c (pad 0)
            base[2 * D * DP + DP + i] = scale * uv;    // u (pad 0)
            base[2 * D * DP + 2 * DP + i] = (i < D) ? hwv * bv[i] : 0.f;   // bvh
        }
        if (tid == 0) {
            float s = 0.f;
            for (int e = 0; e < D; ++e) s += bq[e] * bk[e];
            base[2 * D * DP + 3 * DP] = scale * s;     // s0
        }
    } else {
        int i2 = blk - 12;
        int b = i2 / 144, chunk = i2 % 144;
        const float4* xb = (const float4*)(x + (size_t)b * 3 * HWPX + chunk * 3072);
        float m = 0.f;
        for (int j = tid; j < 768; j += 256) {
            float4 v = xb[j];
            m = fmaxf(m, fmaxf(fmaxf(v.x, v.y), fmaxf(v.z, v.w)));
        }
        for (int off = 32; off; off >>= 1)
            m = fmaxf(m, __shfl_down(m, off));
        if ((tid & 63) == 0) sm[tid >> 6] = m;
        __syncthreads();
        if (tid == 0) {
            float mm = fmaxf(fmaxf(sm[0], sm[1]), fmaxf(sm[2], sm[3]));
            atomicMax((int*)&ws[b], __float_as_int(mm));  // poison is negative; mm>=0 wins
        }
    }
}

// ---------------- stage3: p=1, 6 heads, one window/thread (proven at 216us) ----------------
__global__ __launch_bounds__(256) void attn3(
    const float* __restrict__ in, float* __restrict__ out,
    const float* __restrict__ wsw)
{
    constexpr int DP = 4;
    __shared__ __align__(16) float scell[324 * DP];   // 18x18 cells
    __shared__ __align__(16) float sw[6 * HS3];

    const int tid = threadIdx.x;
    const int b = blockIdx.z;
    const int BWY = blockIdx.y * 16, BWX = blockIdx.x * 16;
    const float* inb = in + (size_t)b * 3 * HWPX;

    for (int i = tid; i < 240; i += 256) sw[i] = wsw[i];
    for (int i = tid; i < 972; i += 256) {
        int c = i / 324;
        int rem = i % 324;
        int cy = rem / 18, cx = rem % 18;
        int y = rx(BWY + cy - 1);
        int x = rx(BWX + cx - 1);
        scell[(cy * 18 + cx) * DP + c] = inb[c * HWPX + y * HH + x];
    }
    for (int j = tid; j < 324; j += 256) scell[j * DP + 3] = 0.f;
    __syncthreads();

    const int wx = tid & 15, wy = tid >> 4;
    const float4 t4 = *(const float4*)&scell[((wy + 1) * 18 + wx + 1) * DP];

    float m0 = 0.f, m1 = 0.f, m2 = 0.f;
#pragma unroll 1
    for (int h = 0; h < 6; ++h) {
        const float* hb = &sw[h * HS3];
        float4 qk = *(const float4*)(hb + 24);
        float su = hb[36] + dot4(*(const float4*)(hb + 28), t4);
        qk = fma4s(qk, *(const float4*)(hb + 0), t4.x);
        qk = fma4s(qk, *(const float4*)(hb + 4), t4.y);
        qk = fma4s(qk, *(const float4*)(hb + 8), t4.z);
        float den = 0.f; float4 wt = {0.f, 0.f, 0.f, 0.f};
#pragma unroll
        for (int p = 0; p < 9; ++p) {
            const int di = p / 3, dj = p % 3;
            const float4 cv = *(const float4*)&scell[((wy + di) * 18 + wx + dj) * DP];
            float e = __expf(su + dot4(qk, cv));
            den += e; wt = fma4s(wt, cv, e);
        }
        float wi = 1.f / den;
        wt.x *= wi; wt.y *= wi; wt.z *= wi; wt.w *= wi;
        m0 += hb[32] + dot4(*(const float4*)(hb + 12), wt);
        m1 += hb[33] + dot4(*(const float4*)(hb + 16), wt);
        m2 += hb[34] + dot4(*(const float4*)(hb + 20), wt);
    }
    float* outb = out + (size_t)b * 9 * HWPX;   // ch6..8
    const int gy = BWY + wy, gx = BWX + wx;
    outb[6 * HWPX + gy * HH + gx] = m0;
    outb[7 * HWPX + gy * HH + gx] = m1;
    outb[8 * HWPX + gy * HH + gx] = m2;
}

// ---------------- stage6: p=2, thread per (window, head); 8x8 win x 4 heads ----------------
__global__ __launch_bounds__(256) void attn6(
    const float* __restrict__ cat, float* __restrict__ catOut,
    const float* __restrict__ wsw)
{
    __shared__ __align__(16) float scell[1200];   // 10x10 cells x 12
    __shared__ __align__(16) float sw[1312];      // 4 x HS6
    __shared__ float comb[3072];                  // [4][64][12]

    const int tid = threadIdx.x;
    const int b = blockIdx.z;
    const int BCX = blockIdx.x * 8, BCY = blockIdx.y * 8;
    const float* inb = cat + (size_t)b * 9 * HWPX + 6 * HWPX;   // X3 (ch6-8)

    for (int i = tid; i < 328; i += 256)
        ((float4*)sw)[i] = ((const float4*)wsw)[i];
    const int by0 = 2 * BCY - 2, bx0 = 2 * BCX - 2;
    for (int i = tid; i < 1200; i += 256) {
        int c = i / 400; int rem = i - c * 400;
        int row = rem / 20, col = rem % 20;
        int gy = rx(by0 + row), gx = rx(bx0 + col);
        scell[((row >> 1) * 10 + (col >> 1)) * 12 + c * 4 + (row & 1) * 2 + (col & 1)]
            = inb[c * HWPX + gy * HH + gx];
    }
    __syncthreads();

    const int h = tid >> 6, w = tid & 63;
    const int wx = w & 7, wy = w >> 3;
    const float* hb = &sw[h * HS6];

    const float4* cc4 = (const float4*)&scell[((wy + 1) * 10 + (wx + 1)) * 12];
    const float4 t40 = cc4[0], t41 = cc4[1], t42 = cc4[2];

    float4 qk0 = *(const float4*)(hb + 288);
    float4 qk1 = *(const float4*)(hb + 292);
    float4 qk2 = *(const float4*)(hb + 296);
    float su = hb[324] + dot4(*(const float4*)(hb + 300), t40)
             + dot4(*(const float4*)(hb + 304), t41)
             + dot4(*(const float4*)(hb + 308), t42);
#pragma unroll
    for (int a = 0; a < 12; ++a) {
        const float t = f4c(a < 4 ? t40 : (a < 8 ? t41 : t42), a & 3);
        const float4* Mr = (const float4*)(hb + 12 * a);
        qk0 = fma4s(qk0, Mr[0], t);
        qk1 = fma4s(qk1, Mr[1], t);
        qk2 = fma4s(qk2, Mr[2], t);
    }
    float den = 0.f;
    float4 wt0 = {0,0,0,0}, wt1 = {0,0,0,0}, wt2 = {0,0,0,0};
#pragma unroll
    for (int p = 0; p < 9; ++p) {
        const int di = p / 3, dj = p % 3;
        const float4* cp = (const float4*)&scell[((wy + di) * 10 + (wx + dj)) * 12];
        const float4 c0 = cp[0], c1 = cp[1], c2 = cp[2];
        float e = __expf(su + dot4(qk0, c0) + dot4(qk1, c1) + dot4(qk2, c2));
        den += e;
        wt0 = fma4s(wt0, c0, e);
        wt1 = fma4s(wt1, c1, e);
        wt2 = fma4s(wt2, c2, e);
    }
    const float wi = 1.f / den;
    wt0.x *= wi; wt0.y *= wi; wt0.z *= wi; wt0.w *= wi;
    wt1.x *= wi; wt1.y *= wi; wt1.z *= wi; wt1.w *= wi;
    wt2.x *= wi; wt2.y *= wi; wt2.z *= wi; wt2.w *= wi;

    float* cbp = &comb[(h * 64 + w) * 12];
#pragma unroll
    for (int e = 0; e < 12; ++e) {
        const float4* Wr = (const float4*)(hb + 144 + 12 * e);
        cbp[e] = hb[312 + e] + dot4(Wr[0], wt0) + dot4(Wr[1], wt1) + dot4(Wr[2], wt2);
    }
    __syncthreads();

    float* outb = catOut + (size_t)b * 9 * HWPX + 3 * HWPX;   // ch3-5
    for (int i = tid; i < 768; i += 256) {
        int w2 = i / 12, e = i % 12;
        float v = comb[w2 * 12 + e] + comb[(64 + w2) * 12 + e]
                + comb[(128 + w2) * 12 + e] + comb[(192 + w2) * 12 + e];
        int c = e >> 2, r = (e >> 1) & 1, s = e & 1;
        int gy = 2 * (BCY + (w2 >> 3)) + r, gx = 2 * (BCX + (w2 & 7)) + s;
        outb[c * HWPX + gy * HH + gx] = v;
    }
}

// ---------------- stage9: p=3, 4-lane team per (window, head); 8x4 win x 2 heads ----------------
__global__ __launch_bounds__(256) void attn9(
    const float* __restrict__ cat, float* __restrict__ catOut,
    const float* __restrict__ wsw)
{
    __shared__ __align__(16) float scell[2160];   // 60 cells x 36 (elems 27..31 zeroed)
    __shared__ __align__(16) float sw[3656];      // 2 x HS9
    __shared__ float comb[1728];                  // [2][32][27]

    const int tid = threadIdx.x;
    const int b = blockIdx.z;
    const int BCX = blockIdx.x * 8, BCY = blockIdx.y * 4;
    const float* inb = cat + (size_t)b * 9 * HWPX + 3 * HWPX;   // X6 (ch3-5)

    for (int i = tid; i < 914; i += 256)
        ((float4*)sw)[i] = ((const float4*)wsw)[i];
    const int by0 = 3 * BCY - 3, bx0 = 3 * BCX - 3;
    for (int i = tid; i < 1620; i += 256) {
        int c = i / 540; int rem = i - c * 540;
        int row = rem / 30, col = rem % 30;
        int gy = rx(by0 + row), gx = rx(bx0 + col);
        scell[((row / 3) * 10 + (col / 3)) * 36 + c * 9 + (row % 3) * 3 + (col % 3)]
            = inb[c * HWPX + gy * HH + gx];
    }
    for (int i = tid; i < 300; i += 256) scell[(i / 5) * 36 + 27 + (i % 5)] = 0.f;
    __syncthreads();

    const int t = tid & 3, team = tid >> 2;
    const int h = team >> 5, w = team & 31;
    const int wx = w & 7, wy = w >> 3;
    const int k0 = t, k1 = t + 4;          // two f4 slices of DP=32 per lane
    const float* hb = &sw[h * HS9];

    const float4* cc4 = (const float4*)&scell[((wy + 1) * 10 + (wx + 1)) * 36];
    float4 t4r[8];
#pragma unroll
    for (int k = 0; k < 8; ++k) t4r[k] = cc4[k];

    float4 qk0 = *(const float4*)(hb + 1728 + 4 * k0);
    float4 qk1 = *(const float4*)(hb + 1728 + 4 * k1);
#pragma unroll
    for (int a = 0; a < 27; ++a) {
        const float tv = f4c(t4r[a >> 2], a & 3);
        qk0 = fma4s(qk0, *(const float4*)(hb + a * 32 + 4 * k0), tv);
        qk1 = fma4s(qk1, *(const float4*)(hb + a * 32 + 4 * k1), tv);
    }
    // u.t4 partial via LDS reads (avoid runtime reg-array index)
    float upart = dot4(*(const float4*)(hb + 1760 + 4 * k0), cc4[k0])
                + dot4(*(const float4*)(hb + 1760 + 4 * k1), cc4[k1]);
    const float s0v = hb[1824];

    float den = 0.f;
    float4 wt0 = {0,0,0,0}, wt1 = {0,0,0,0};
#pragma unroll
    for (int p = 0; p < 9; ++p) {
        const int di = p / 3, dj = p % 3;
        const float4* cp = (const float4*)&scell[((wy + di) * 10 + (wx + dj)) * 36];
        const float4 c0 = cp[k0], c1 = cp[k1];
        float part = upart + dot4(qk0, c0) + dot4(qk1, c1);
        part += __shfl_xor(part, 1);
        part += __shfl_xor(part, 2);
        const float e = __expf(s0v + part);
        den += e;
        wt0 = fma4s(wt0, c0, e);
        wt1 = fma4s(wt1, c1, e);
    }
    const float wi = 1.f / den;
    wt0.x *= wi; wt0.y *= wi; wt0.z *= wi; wt0.w *= wi;
    wt1.x *= wi; wt1.y *= wi; wt1.z *= wi; wt1.w *= wi;

    float* cbp = &comb[(h * 32 + w) * 27];
#pragma unroll
    for (int e = 0; e < 27; ++e) {
        float po = dot4(*(const float4*)(hb + 864 + e * 32 + 4 * k0), wt0)
                 + dot4(*(const float4*)(hb + 864 + e * 32 + 4 * k1), wt1);
        po += __shfl_xor(po, 1);
        po += __shfl_xor(po, 2);
        if (t == 0) cbp[e] = po + hb[1792 + e];
    }
    __syncthreads();

    float* outb = catOut + (size_t)b * 9 * HWPX;   // ch0-2
    for (int i = tid; i < 864; i += 256) {
        int w2 = i / 27, e = i % 27;
        float v = comb[w2 * 27 + e] + comb[(32 + w2) * 27 + e];
        int c = e / 9, r = (e % 9) / 3, s = e % 3;
        int gy = 3 * (BCY + (w2 >> 3)) + r, gx = 3 * (BCX + (w2 & 7)) + s;
        outb[c * HWPX + gy * HH + gx] = v;
    }
}

// ---------------- conv0 (5x5, zero-pad 2) + final elementwise; 32x16 tile, 2 px/thread ----------------
__global__ __launch_bounds__(256) void conv_final(
    const float* __restrict__ cat, const float* __restrict__ cw,
    const float* __restrict__ cb, const float* __restrict__ x,
    const float* __restrict__ xg, float* __restrict__ out)
{
    __shared__ float tile[9][20][40];
    __shared__ float sw[678];
    const int tid = threadIdx.x;
    const int b = blockIdx.z;
    const int bx = blockIdx.x * 32, by = blockIdx.y * 16;
    const float* catb = cat + (size_t)b * 9 * HWPX;

    for (int i = tid; i < 678; i += 256) sw[i] = (i < 675) ? cw[i] : cb[i - 675];
    for (int i = tid; i < 1800; i += 256) {
        int ci = i / 200, rem = i % 200;
        int row = rem / 10, c4 = rem % 10;
        int y = by + row - 2, xx = bx - 4 + 4 * c4;
        float4 v = {0.f, 0.f, 0.f, 0.f};
        if (y >= 0 && y < HH && xx >= 0 && xx <= HH - 4)
            v = *(const float4*)&catb[ci * HWPX + y * HH + xx];
        *(float4*)&tile[ci][row][4 * c4] = v;
    }
    __syncthreads();

    const int pxx = tid & 31, py0 = (tid >> 5) * 2;
    float acc[2][3];
    acc[0][0] = acc[1][0] = sw[675];
    acc[0][1] = acc[1][1] = sw[676];
    acc[0][2] = acc[1][2] = sw[677];

#pragma unroll 1
    for (int ci = 0; ci < 9; ++ci) {
        float rv[6][5];
#pragma unroll
        for (int rr = 0; rr < 6; ++rr)
#pragma unroll
            for (int cc = 0; cc < 5; ++cc)
                rv[rr][cc] = tile[ci][py0 + rr][pxx + 2 + cc];
#pragma unroll
        for (int ky = 0; ky < 5; ++ky)
#pragma unroll
            for (int kx = 0; kx < 5; ++kx) {
                const float w0 = sw[(0 * 9 + ci) * 25 + ky * 5 + kx];
                const float w1 = sw[(1 * 9 + ci) * 25 + ky * 5 + kx];
                const float w2 = sw[(2 * 9 + ci) * 25 + ky * 5 + kx];
                const float ta = rv[ky][kx], tb = rv[ky + 1][kx];
                acc[0][0] += ta * w0; acc[0][1] += ta * w1; acc[0][2] += ta * w2;
                acc[1][0] += tb * w0; acc[1][1] += tb * w1; acc[1][2] += tb * w2;
            }
    }

    const float xgv = xg[b];
#pragma unroll
    for (int jj = 0; jj < 2; ++jj) {
        const int gy = by + py0 + jj, gx = bx + pxx;
#pragma unroll
        for (int co = 0; co < 3; ++co) {
            const float x0 = fmaxf(acc[jj][co], 0.f);
            const float xv = x[((size_t)(b * 3 + co)) * HWPX + gy * HH + gx];
            out[((size_t)(b * 3 + co)) * HWPX + gy * HH + gx] =
                fmaxf(xv * x0 + xgv - x0, 0.f);
        }
    }
}

// ---------------- launch ----------------
extern "C" void kernel_launch(void* const* d_in, const int* in_sizes, int n_in,
                              void* d_out, int out_size, void* d_ws, size_t ws_size,
                              hipStream_t stream) {
    const float* x   = (const float*)d_in[0];
    const float* w3q = (const float*)d_in[1];
    const float* b3q = (const float*)d_in[2];
    const float* w3k = (const float*)d_in[3];
    const float* b3k = (const float*)d_in[4];
    const float* w3v = (const float*)d_in[5];
    const float* b3v = (const float*)d_in[6];
    const float* hw3 = (const float*)d_in[7];
    const float* w6q = (const float*)d_in[8];
    const float* b6q = (const float*)d_in[9];
    const float* w6k = (const float*)d_in[10];
    const float* b6k = (const float*)d_in[11];
    const float* w6v = (const float*)d_in[12];
    const float* b6v = (const float*)d_in[13];
    const float* hw6 = (const float*)d_in[14];
    const float* w9q = (const float*)d_in[15];
    const float* b9q = (const float*)d_in[16];
    const float* w9k = (const float*)d_in[17];
    const float* b9k = (const float*)d_in[18];
    const float* w9v = (const float*)d_in[19];
    const float* b9v = (const float*)d_in[20];
    const float* hw9 = (const float*)d_in[21];
    const float* c0w = (const float*)d_in[22];
    const float* c0b = (const float*)d_in[23];

    float* out = (float*)d_out;
    float* ws  = (float*)d_ws;
    float* cat = ws + CATOFF;

    pre_xg<<<300, 256, 0, stream>>>(
        w3q, b3q, w3k, b3k, w3v, b3v, hw3,
        w6q, b6q, w6k, b6k, w6v, b6v, hw6,
        w9q, b9q, w9k, b9k, w9v, b9v, hw9, x, ws);

    // stage3: 16x16 windows/block -> cat ch6-8
    attn3<<<dim3(24, 24, 2), 256, 0, stream>>>(x, cat, ws + WOFF3);
    // stage6: 8x8 windows x 4 heads/block -> cat ch3-5
    attn6<<<dim3(24, 24, 2), 256, 0, stream>>>(cat, cat, ws + WOFF6);
    // stage9: 8x4 windows x 2 heads x 4-lane teams/block -> cat ch0-2
    attn9<<<dim3(16, 32, 2), 256, 0, stream>>>(cat, cat, ws + WOFF9);

    conv_final<<<dim3(12, 24, 2), 256, 0, stream>>>(cat, c0w, c0b, x, ws, out);
}